// Round 4
// baseline (3425.716 us; speedup 1.0000x reference)
//
#include <hip/hip_runtime.h>
#include <cstdint>
#include <cstddef>

// Problem constants (fixed by the reference)
#define T_STEPS 256
#define BATCH   256
#define DIN     512
#define HID     1024
#define KTOT    1536   // DIN + HID
#define NOUT    4096   // 4*HID
#define BHSZ    ((size_t)BATCH * HID)   // 262144 elems

typedef __bf16 bf16;
typedef __bf16 bf16x4 __attribute__((ext_vector_type(4)));
typedef __bf16 bf16x8 __attribute__((ext_vector_type(8)));
typedef float  f32x4  __attribute__((ext_vector_type(4)));

// ---------------------------------------------------------------------------
// async global->LDS, 16B per lane (HW: wave-uniform LDS base + lane*16)
__device__ __forceinline__ void gload16(const void* g, void* l) {
  __builtin_amdgcn_global_load_lds(
      (const __attribute__((address_space(1))) void*)g,
      (__attribute__((address_space(3))) void*)l, 16, 0, 0);
}

// ---------------------------------------------------------------------------
// Gate-interleaved transposed weights: Wt[(j>>4)*64 + gate*16 + (j&15)][k]
// (verified in rounds 1-2)
__global__ void convert_w_kernel(const float* __restrict__ Wf, const float* __restrict__ Wi,
                                 const float* __restrict__ Wg, const float* __restrict__ Wo,
                                 bf16* __restrict__ Wt) {
  __shared__ float tile[64][17];
  const int k0 = blockIdx.x * 64;
  const int jb = blockIdx.y;
  const int j0 = jb * 16;
  const int t  = threadIdx.x;
  const float* srcs[4] = {Wf, Wi, Wg, Wo};
#pragma unroll
  for (int g = 0; g < 4; ++g) {
    const float* src = srcs[g];
    {
      const int jl = t & 15, kb = t >> 4;
#pragma unroll
      for (int r = 0; r < 4; ++r) {
        const int kl = kb + 16 * r;
        tile[kl][jl] = src[(size_t)(k0 + kl) * HID + (j0 + jl)];
      }
    }
    __syncthreads();
    {
      const int kk = t & 63, jl4 = t >> 6;
#pragma unroll
      for (int r = 0; r < 4; ++r) {
        const int jl = jl4 + 4 * r;
        Wt[(size_t)(jb * 64 + g * 16 + jl) * KTOT + (k0 + kk)] = (bf16)tile[kk][jl];
      }
    }
    __syncthreads();
  }
}

// ---------------------------------------------------------------------------
// Persistent LSTM. 256 blocks (1/CU) x 256 threads (4 waves).
// Block tile: BM=64 batch rows (mblk) x BN=64 Wt-rows (nblk) = 16 j x 4 gates.
// BK=128, 12 K-tiles/step; waves split K (quarter each -> every staged byte
// read from LDS exactly once); one-round cross-wave reduce; gates fused in
// epilogue; c lives in VGPRs for the whole sequence.
// h handoff: h_t = fp32 out slice t (per-step-fresh addresses). Producers:
// relaxed agent atomic stores (write-through to MALL) + __syncthreads drain +
// per-block flag. Consumers: 64-lane flag poll (relaxed agent loads) then
// normal cached loads (L2-shared within XCD). Stale-line defense: one
// agent-acquire (L2 inv) per block at kernel start.
__global__ __launch_bounds__(256, 1)
void lstm_persist(const bf16* __restrict__ Bt,
                  const float* __restrict__ X,
                  const float* __restrict__ zbF,   // >= 1MB zeros
                  float* __restrict__ outF,
                  const float* __restrict__ bf_, const float* __restrict__ bi_,
                  const float* __restrict__ bg_, const float* __restrict__ bo_,
                  unsigned* __restrict__ flags) {  // [T_STEPS][256], zeroed
  __shared__ bf16  sb[2][2][64 * 128];      // 64 KiB: [buf][A=0/B=1]
  __shared__ float redu[4][3][4][64][4];    // 48 KiB reduce region

  const int tid = threadIdx.x, lane = tid & 63, wid = tid >> 6;
  const int bid = blockIdx.x;
  const int xcd = bid & 7, sl = bid >> 3;
  const int nblk = xcd * 8 + (sl & 7);  // XCD owns contiguous N-slice (L2 reuse)
  const int mblk = sl >> 3;
  const int bm0 = mblk * 64;
  const int bn0 = nblk * 64;
  const int fr = lane & 15, fq = lane >> 4;

  // once-per-launch agent acquire: invalidates stale (harness-memset) L2 lines
  if (tid == 0)
    (void)__hip_atomic_load(flags, __ATOMIC_ACQUIRE, __HIP_MEMORY_SCOPE_AGENT);
  __syncthreads();

  const int j = nblk * 16 + fr;
  const float bfv = bf_[j], biv = bi_[j], bgv = bg_[j], bov = bo_[j];
  float cr4[4] = {0.f, 0.f, 0.f, 0.f};

  f32x4 sF[8];   // reg-staged A (fp32); exactly one tile in flight at a time

  auto stage = [&](int t2, int k2, int buf) {
    // ---- A-part: fp32 source (X, h = out slice t2-1, or zeros)
    const float* src; int ldx, kloc;
    if (k2 < 4) {
      src = X + (size_t)t2 * BATCH * DIN; ldx = DIN; kloc = k2 * 128;
    } else {
      if (k2 == 4 && t2 > 0) {
        const unsigned* f = flags + (size_t)(t2 - 1) * 256 + mblk * 64;
        const unsigned long long tt0 = __builtin_amdgcn_s_memrealtime();
        for (;;) {
          unsigned v = __hip_atomic_load(f + lane, __ATOMIC_RELAXED,
                                         __HIP_MEMORY_SCOPE_AGENT);
          if (__all(v != 0)) break;
          __builtin_amdgcn_s_sleep(2);
          if (__builtin_amdgcn_s_memrealtime() - tt0 > (1ULL << 22)) break; // fail-soft
        }
        asm volatile("" ::: "memory");
        __builtin_amdgcn_sched_barrier(0);
      }
      src = (t2 == 0) ? zbF : outF + (size_t)(t2 - 1) * BHSZ;
      ldx = HID; kloc = k2 * 128 - 512;
    }
#pragma unroll
    for (int i = 0; i < 8; ++i) {           // 8 x f32x4 per lane = 32 KB/block
      const int flat = wid * 512 + i * 64 + lane;
      const int row = flat >> 5, u = flat & 31;
      sF[i] = *(const f32x4*)(src + (size_t)(bm0 + row) * ldx + kloc + u * 4);
    }
    // ---- B-part: DMA, 16 chunks of 1KB (4 rows x 128 elems each)
    const int k0 = k2 * 128;
#pragma unroll
    for (int cc = 0; cc < 4; ++cc) {
      const int c = wid * 4 + cc;           // 0..15
      const int row = 4 * c + (lane >> 4);
      const int slot = (lane & 15) ^ (row & 15);  // pre-swizzled source (rule #21)
      gload16(Bt + (size_t)(bn0 + row) * KTOT + k0 + slot * 8, &sb[buf][1][c * 512]);
    }
  };

  auto finishA = [&](int buf) {  // sF -> bf16 -> XOR-swizzled LDS
#pragma unroll
    for (int i = 0; i < 8; ++i) {
      const int flat = wid * 512 + i * 64 + lane;
      const int row = flat >> 5, u = flat & 31;
      bf16x4 v;
      v[0] = (bf16)sF[i][0]; v[1] = (bf16)sF[i][1];
      v[2] = (bf16)sF[i][2]; v[3] = (bf16)sF[i][3];
      *(bf16x4*)(&sb[buf][0][row * 128 + ((u >> 1) ^ (row & 15)) * 8 + (u & 1) * 4]) = v;
    }
    asm volatile("s_waitcnt lgkmcnt(0)" ::: "memory");
    __builtin_amdgcn_sched_barrier(0);
  };

  // step-0 prologue: tile 0 staged+finished, tile 1 staged
  stage(0, 0, 0);
  asm volatile("s_waitcnt vmcnt(4)" ::: "memory");   // sF landed (own B-DMA may fly)
  finishA(0);
  stage(0, 1, 1);

  const int gsl = wid * 4 + fq;   // this lane's k-granule (16B) in the 128-elem row

#pragma unroll 1
  for (int t = 0; t < T_STEPS; ++t) {
    f32x4 acc[4][4] = {};
#pragma unroll
    for (int kt = 0; kt < 12; ++kt) {
      const int buf = kt & 1;
      // tile kt fully landed; tile kt+1's 12 ops may remain in flight
      if (kt == 11) asm volatile("s_waitcnt vmcnt(0)" ::: "memory");
      else          asm volatile("s_waitcnt vmcnt(12)" ::: "memory");
      __builtin_amdgcn_s_barrier();               // bar1: tile kt in LDS
      bf16x8 af[4], bfr[4];
#pragma unroll
      for (int mf = 0; mf < 4; ++mf) {
        const int row = mf * 16 + fr;
        af[mf] = *(const bf16x8*)(&sb[buf][0][row * 128 + ((gsl ^ (row & 15)) * 8)]);
      }
#pragma unroll
      for (int nf = 0; nf < 4; ++nf) {
        const int row = nf * 16 + fr;
        bfr[nf] = *(const bf16x8*)(&sb[buf][1][row * 128 + ((gsl ^ (row & 15)) * 8)]);
      }
      asm volatile("s_waitcnt lgkmcnt(0)" ::: "memory");
      __builtin_amdgcn_sched_barrier(0);
      __builtin_amdgcn_s_barrier();               // bar2: buf free for restage
      if (kt < 11) finishA(buf ^ 1);              // tile kt+1 A write (compiler waits sF)
      if (kt < 10) stage(t, kt + 2, buf);         // tile kt+2 (same step only)
#pragma unroll
      for (int mf = 0; mf < 4; ++mf)
#pragma unroll
        for (int nf = 0; nf < 4; ++nf)
          acc[mf][nf] = __builtin_amdgcn_mfma_f32_16x16x32_bf16(af[mf], bfr[nf],
                                                                acc[mf][nf], 0, 0, 0);
    }

    // ---- one-round cross-wave K-reduce: wave w ends owning m-frag w
#pragma unroll
    for (int m = 0; m < 4; ++m) {
      if (m != wid) {
        const int s = (wid < m) ? wid : wid - 1;
#pragma unroll
        for (int nf = 0; nf < 4; ++nf)
          *(f32x4*)(&redu[m][s][nf][lane][0]) = acc[m][nf];
      }
    }
    asm volatile("s_waitcnt lgkmcnt(0)" ::: "memory");
    __builtin_amdgcn_s_barrier();
    f32x4 accF[4];
#pragma unroll
    for (int nf = 0; nf < 4; ++nf) {
      f32x4 a;
      if (wid == 0)      a = acc[0][nf];
      else if (wid == 1) a = acc[1][nf];
      else if (wid == 2) a = acc[2][nf];
      else               a = acc[3][nf];
#pragma unroll
      for (int s = 0; s < 3; ++s)
        a += *(const f32x4*)(&redu[wid][s][nf][lane][0]);
      accF[nf] = a;
    }

    // ---- epilogue: gates (nf = gate), c/h update, agent stores
    {
      float* outSl = outF + (size_t)t * BHSZ;
      const int mBase = bm0 + wid * 16 + fq * 4;
#pragma unroll
      for (int r = 0; r < 4; ++r) {
        const float fg = 1.f / (1.f + expf(-(accF[0][r] + bfv)));
        const float ig = 1.f / (1.f + expf(-(accF[1][r] + biv)));
        const float gg = tanhf(accF[2][r] + bgv);
        const float og = 1.f / (1.f + expf(-(accF[3][r] + bov)));
        cr4[r] = fg * cr4[r] + ig * gg;
        const float h = og * tanhf(cr4[r]);
        __hip_atomic_store(&outSl[(size_t)(mBase + r) * HID + j], h,
                           __ATOMIC_RELAXED, __HIP_MEMORY_SCOPE_AGENT);
      }
      if (t == T_STEPS - 1) {
        float* cxp = outF + (size_t)(T_STEPS + 1) * BHSZ;
#pragma unroll
        for (int r = 0; r < 4; ++r)
          __hip_atomic_store(&cxp[(size_t)(mBase + r) * HID + j], cr4[r],
                             __ATOMIC_RELAXED, __HIP_MEMORY_SCOPE_AGENT);
      }
    }
    __syncthreads();   // drains every wave's h stores (vmcnt 0) + block barrier
    if (tid == 0)
      __hip_atomic_store(&flags[(size_t)t * 256 + mblk * 64 + nblk], 1u,
                         __ATOMIC_RELAXED, __HIP_MEMORY_SCOPE_AGENT);
    // next-step prologue (x-only tiles; h-tiles gated by the spin at k2==4)
    if (t + 1 < T_STEPS) {
      stage(t + 1, 0, 0);
      asm volatile("s_waitcnt vmcnt(4)" ::: "memory");
      finishA(0);
      stage(t + 1, 1, 1);
    }
  }
}

// ---------------------------------------------------------------------------
extern "C" void kernel_launch(void* const* d_in, const int* in_sizes, int n_in,
                              void* d_out, int out_size, void* d_ws, size_t ws_size,
                              hipStream_t stream) {
  const float* X   = (const float*)d_in[0];
  const float* Wf  = (const float*)d_in[1];
  const float* bf_ = (const float*)d_in[2];
  const float* Wi  = (const float*)d_in[3];
  const float* bi_ = (const float*)d_in[4];
  const float* Wg  = (const float*)d_in[5];
  const float* bg_ = (const float*)d_in[6];
  const float* Wo  = (const float*)d_in[7];
  const float* bo_ = (const float*)d_in[8];
  float* out = (float*)d_out;

  const size_t WtB   = (size_t)NOUT * KTOT * 2;          // 12.58 MB
  const size_t zBb   = BHSZ * 4;                         // 1 MB zeros
  const size_t flagB = (size_t)T_STEPS * 256 * 4;        // 256 KB

  char* ws = (char*)d_ws;
  bf16*     Wt    = (bf16*)ws;      ws += WtB;
  float*    zbF   = (float*)(void*)ws; ws += zBb;
  unsigned* flags = (unsigned*)(void*)ws;

  // zeros for h0 + flag array (both re-zeroed every launch -> deterministic)
  hipMemsetAsync(zbF, 0, zBb + flagB, stream);

  convert_w_kernel<<<dim3(KTOT / 64, NOUT / 64), 256, 0, stream>>>(Wf, Wi, Wg, Wo, Wt);

  lstm_persist<<<256, 256, 0, stream>>>(Wt, X, zbF, out,
                                        bf_, bi_, bg_, bo_, flags);

  // hx = outputs[T-1] (cx stored by the kernel at (T+1)*BHSZ)
  hipMemcpyAsync(out + (size_t)T_STEPS * BHSZ, out + (size_t)(T_STEPS - 1) * BHSZ,
                 BHSZ * 4, hipMemcpyDeviceToDevice, stream);
}

// Round 5
// 2686.997 us; speedup vs baseline: 1.2749x; 1.2749x over previous
//
#include <hip/hip_runtime.h>
#include <cstdint>
#include <cstddef>

// Problem constants (fixed by the reference)
#define T_STEPS 256
#define BATCH   256
#define DIN     512
#define HID     1024
#define KTOT    1536   // DIN + HID
#define NOUT    4096   // 4*HID
#define BHSZ    ((size_t)BATCH * HID)   // 262144 elems
#define NTILE   12                      // K-tiles per step (BK=128)
#define GTOT    (T_STEPS * NTILE)       // 3072 global tiles

typedef __bf16 bf16;
typedef __bf16 bf16x4 __attribute__((ext_vector_type(4)));
typedef __bf16 bf16x8 __attribute__((ext_vector_type(8)));
typedef float  f32x4  __attribute__((ext_vector_type(4)));

// ---------------------------------------------------------------------------
// async global->LDS, 16B per lane (HW: wave-uniform LDS base + lane*16)
__device__ __forceinline__ void gload16(const void* g, void* l) {
  __builtin_amdgcn_global_load_lds(
      (const __attribute__((address_space(1))) void*)g,
      (__attribute__((address_space(3))) void*)l, 16, 0, 0);
}

// cross-XCD-visible bf16 store (write-through to MALL)
__device__ __forceinline__ void store_bf16_sc(bf16* p, bf16 v) {
  unsigned short u = __builtin_bit_cast(unsigned short, v);
  asm volatile("global_store_short %0, %1, off sc0 sc1" :: "v"(p), "v"(u) : "memory");
}

// ---------------------------------------------------------------------------
// Gate-interleaved transposed weights: Wt[(j>>4)*64 + gate*16 + (j&15)][k]
// (verified in rounds 1-4)
__global__ void convert_w_kernel(const float* __restrict__ Wf, const float* __restrict__ Wi,
                                 const float* __restrict__ Wg, const float* __restrict__ Wo,
                                 bf16* __restrict__ Wt) {
  __shared__ float tile[64][17];
  const int k0 = blockIdx.x * 64;
  const int jb = blockIdx.y;
  const int j0 = jb * 16;
  const int t  = threadIdx.x;
  const float* srcs[4] = {Wf, Wi, Wg, Wo};
#pragma unroll
  for (int g = 0; g < 4; ++g) {
    const float* src = srcs[g];
    {
      const int jl = t & 15, kb = t >> 4;
#pragma unroll
      for (int r = 0; r < 4; ++r) {
        const int kl = kb + 16 * r;
        tile[kl][jl] = src[(size_t)(k0 + kl) * HID + (j0 + jl)];
      }
    }
    __syncthreads();
    {
      const int kk = t & 63, jl4 = t >> 6;
#pragma unroll
      for (int r = 0; r < 4; ++r) {
        const int jl = jl4 + 4 * r;
        Wt[(size_t)(jb * 64 + g * 16 + jl) * KTOT + (k0 + kk)] = (bf16)tile[kk][jl];
      }
    }
    __syncthreads();
  }
}

// fp32 -> bf16 convert of one timestep slice (grid.y = t)  [MODE 0 only]
__global__ void convert_x_kernel(const float* __restrict__ X, bf16* __restrict__ xb) {
  const int t = blockIdx.y;
  const int i = blockIdx.x * blockDim.x + threadIdx.x;  // 0 .. B*D/4-1
  const float4 v = ((const float4*)(X + (size_t)t * BATCH * DIN))[i];
  bf16x4 o;
  o[0] = (bf16)v.x; o[1] = (bf16)v.y; o[2] = (bf16)v.z; o[3] = (bf16)v.w;
  ((bf16x4*)(xb + (size_t)t * BATCH * DIN))[i] = o;
}

// ---------------------------------------------------------------------------
// Persistent LSTM. 256 blocks (1/CU) x 512 threads (8 waves = 2/SIMD).
// Block tile: 64 batch rows x 64 Wt rows (16 j x 4 gates). BK=128, 12 tiles.
// Wave (mh, kq): mh = M-half (2 M-frags), kq = K-quarter (1 kseg/tile).
// A: direct global->VGPR in MFMA frag layout (1-tile prefetch). B: DMA->LDS
// (XOR-swizzled via pre-swizzled source), 3 buffers, 1 barrier/tile,
// counted vmcnt gate. Cross-wave K-reduce (64KB LDS) once per step; gates
// fused in epilogue (2 rows/lane); c persists in VGPRs.
// MODE 0: A = bf16 (xb + hseq in ws, fresh addresses/step).
// MODE 1: A = fp32 (X direct + h = fp32 out slices, round-3-proven).
template<int MODE>
__global__ __launch_bounds__(512, 2)
void lstm_persist(const bf16* __restrict__ Bt,
                  const float* __restrict__ X,
                  const bf16* __restrict__ xb,     // MODE 0
                  bf16* __restrict__ hseq,         // MODE 0
                  const float* __restrict__ zbF,   // >= 1MB zeros
                  float* __restrict__ outF,
                  const float* __restrict__ bf_, const float* __restrict__ bi_,
                  const float* __restrict__ bg_, const float* __restrict__ bo_,
                  unsigned* __restrict__ flags) {  // [T_STEPS][256], zeroed
  __shared__ bf16  sb[3][64 * 128];     // 48 KiB, B tiles only
  __shared__ f32x4 redu[8][8][64];      // 64 KiB reduce region

  const int tid = threadIdx.x, lane = tid & 63, wid = tid >> 6;
  const int mh = wid >> 2, kq = wid & 3;
  const int bid = blockIdx.x;
  const int xcd = bid & 7, sl = bid >> 3;
  const int nblk = xcd * 8 + (sl & 7);  // XCD owns contiguous N-slice (L2 reuse)
  const int mblk = sl >> 3;
  const int bm0 = mblk * 64;
  const int bn0 = nblk * 64;
  const int fr = lane & 15, fq = lane >> 4;

  // once-per-launch agent acquire: invalidate stale L2 lines (cross-launch)
  if (tid == 0)
    (void)__hip_atomic_load(flags, __ATOMIC_ACQUIRE, __HIP_MEMORY_SCOPE_AGENT);
  __syncthreads();

  const int j = nblk * 16 + fr;
  const float bfv = bf_[j], biv = bi_[j], bgv = bg_[j], bov = bo_[j];
  float cr0 = 0.f, cr1 = 0.f;          // 2 persistent c values per lane

  bf16x8 afp[2][2];                    // MODE 0: A frag prefetch (ping-pong)
  f32x4  sfp[2][2][2];                 // MODE 1: fp32 staged A

  auto pollFlags = [&](int tprev) {
    const unsigned* f = flags + (size_t)tprev * 256 + mblk * 64;
    const unsigned long long tt0 = __builtin_amdgcn_s_memrealtime();
    for (;;) {
      unsigned v = __hip_atomic_load(f + lane, __ATOMIC_RELAXED,
                                     __HIP_MEMORY_SCOPE_AGENT);
      if (__all(v != 0)) break;
      __builtin_amdgcn_s_sleep(2);
      if (__builtin_amdgcn_s_memrealtime() - tt0 > (1ULL << 22)) break; // fail-soft
    }
    asm volatile("" ::: "memory");
    __builtin_amdgcn_sched_barrier(0);
  };

  // A-fragment loads for tile (t2, k2) -> prefetch slot p (compile-time p)
  auto loadA = [&](int t2, int k2, int p) {
    if (k2 == 4 && t2 > 0) pollFlags(t2 - 1);
    if (MODE == 0) {
      const bf16* src; int ld;
      if (k2 < 4) { src = xb + (size_t)t2 * BATCH * DIN + k2 * 128; ld = DIN; }
      else {
        src = ((t2 == 0) ? (const bf16*)zbF : hseq + (size_t)(t2 - 1) * BHSZ)
              + (k2 * 128 - 512);
        ld = HID;
      }
#pragma unroll
      for (int mf = 0; mf < 2; ++mf) {
        const int row = bm0 + (mh * 2 + mf) * 16 + fr;
        afp[p][mf] = *(const bf16x8*)(src + (size_t)row * ld + kq * 32 + fq * 8);
      }
    } else {
      const float* src; int ld;
      if (k2 < 4) { src = X + (size_t)t2 * BATCH * DIN + k2 * 128; ld = DIN; }
      else {
        src = ((t2 == 0) ? zbF : outF + (size_t)(t2 - 1) * BHSZ) + (k2 * 128 - 512);
        ld = HID;
      }
#pragma unroll
      for (int mf = 0; mf < 2; ++mf) {
        const int row = bm0 + (mh * 2 + mf) * 16 + fr;
        const float* q = src + (size_t)row * ld + kq * 32 + fq * 8;
        sfp[p][mf][0] = *(const f32x4*)q;
        sfp[p][mf][1] = *(const f32x4*)(q + 4);
      }
    }
  };

  // B tile DMA: 16 chunks of 1KB (4 rows x 128 elems), pre-swizzled source
  auto dmaB = [&](int k2, int buf) {
    const int k0 = k2 * 128;
#pragma unroll
    for (int cc = 0; cc < 2; ++cc) {
      const int c = wid * 2 + cc;                 // 0..15
      const int row = 4 * c + (lane >> 4);
      const int slot = (lane & 15) ^ (row & 15);  // rule #21: inverse-swz source
      gload16(Bt + (size_t)(bn0 + row) * KTOT + k0 + slot * 8, &sb[buf][c * 512]);
    }
  };

  // prologue
  dmaB(0, 0);
  loadA(0, 0, 0);
  dmaB(1, 1);

#pragma unroll 1
  for (int t = 0; t < T_STEPS; ++t) {
    f32x4 acc[2][4] = {};
#pragma unroll
    for (int kt = 0; kt < NTILE; ++kt) {
      // gate: tile kt's B-DMA landed (prefetches stay in flight)
      if (MODE == 0) asm volatile("s_waitcnt vmcnt(4)" ::: "memory");
      else           asm volatile("s_waitcnt vmcnt(6)" ::: "memory");
      __builtin_amdgcn_s_barrier();
      // B fragment reads (this wave's kseg, XOR-deswizzle)
      bf16x8 bfr[4];
#pragma unroll
      for (int nf = 0; nf < 4; ++nf) {
        const int row = nf * 16 + fr;
        const int g = kq * 4 + fq;
        bfr[nf] = *(const bf16x8*)(&sb[kt % 3][row * 128 + ((g ^ (row & 15)) * 8)]);
      }
      asm volatile("s_waitcnt lgkmcnt(0)" ::: "memory");
      __builtin_amdgcn_sched_barrier(0);
      // prefetch: A for tile kt+1, B-DMA for tile kt+2
      { const int k2n = (kt + 1) % NTILE; const int t2 = (kt == 11) ? t + 1 : t;
        if (t2 < T_STEPS) loadA(t2, k2n, (kt + 1) & 1); }
      { const int g2 = t * NTILE + kt + 2;
        if (g2 < GTOT) dmaB(g2 % NTILE, (kt + 2) % 3); }
      // MFMA cluster
      bf16x8 a0, a1;
      if (MODE == 0) { a0 = afp[kt & 1][0]; a1 = afp[kt & 1][1]; }
      else {
#pragma unroll
        for (int e = 0; e < 8; ++e) {
          a0[e] = (bf16)sfp[kt & 1][0][e >> 2][e & 3];
          a1[e] = (bf16)sfp[kt & 1][1][e >> 2][e & 3];
        }
      }
      __builtin_amdgcn_s_setprio(1);
#pragma unroll
      for (int nf = 0; nf < 4; ++nf) {
        acc[0][nf] = __builtin_amdgcn_mfma_f32_16x16x32_bf16(a0, bfr[nf], acc[0][nf], 0, 0, 0);
        acc[1][nf] = __builtin_amdgcn_mfma_f32_16x16x32_bf16(a1, bfr[nf], acc[1][nf], 0, 0, 0);
      }
      __builtin_amdgcn_s_setprio(0);
    }

    // ---- cross-wave K-reduce (4 kq contributions per output)
#pragma unroll
    for (int mf = 0; mf < 2; ++mf)
#pragma unroll
      for (int nf = 0; nf < 4; ++nf)
        redu[wid][mf * 4 + nf][lane] = acc[mf][nf];
    asm volatile("s_waitcnt lgkmcnt(0)" ::: "memory");
    __builtin_amdgcn_s_barrier();

    // owner wave o: M-frag o>>1, row-half o&1; lane handles rows 2*fq+{0,1}
    const int M = wid >> 1, rh = wid & 1;
    const int mh_c = M >> 1, mfl = M & 1;
    float* outSl = outF + (size_t)t * BHSZ;
#pragma unroll
    for (int e = 0; e < 2; ++e) {
      const int rloc = rh * 8 + 2 * fq + e;       // row within 16-row frag
      const int fq_c = rloc >> 2, r_c = rloc & 3;
      float v[4];
#pragma unroll
      for (int nf = 0; nf < 4; ++nf) {
        float s = 0.f;
#pragma unroll
        for (int kqq = 0; kqq < 4; ++kqq)
          s += ((const float*)&redu[mh_c * 4 + kqq][mfl * 4 + nf][fq_c * 16 + fr])[r_c];
        v[nf] = s;
      }
      const float fg = 1.f / (1.f + expf(-(v[0] + bfv)));
      const float ig = 1.f / (1.f + expf(-(v[1] + biv)));
      const float gg = tanhf(v[2] + bgv);
      const float og = 1.f / (1.f + expf(-(v[3] + bov)));
      float& cre = e ? cr1 : cr0;
      cre = fg * cre + ig * gg;
      const float h = og * tanhf(cre);
      const int m = bm0 + M * 16 + rloc;
      const size_t off = (size_t)m * HID + j;
      if (MODE == 0) {
        outSl[off] = h;                                     // harness output
        store_bf16_sc(hseq + (size_t)t * BHSZ + off, (bf16)h);  // consumers
      } else {
        __hip_atomic_store(&outSl[off], h, __ATOMIC_RELAXED,
                           __HIP_MEMORY_SCOPE_AGENT);
      }
      if (t == T_STEPS - 1)
        outF[(size_t)(T_STEPS + 1) * BHSZ + off] = cre;     // cx
    }
    __syncthreads();   // drains all waves' h stores (vmcnt 0) + block barrier
    if (tid == 0)
      __hip_atomic_store(&flags[(size_t)t * 256 + mblk * 64 + nblk], 1u,
                         __ATOMIC_RELAXED, __HIP_MEMORY_SCOPE_AGENT);
  }
}

// ---------------------------------------------------------------------------
extern "C" void kernel_launch(void* const* d_in, const int* in_sizes, int n_in,
                              void* d_out, int out_size, void* d_ws, size_t ws_size,
                              hipStream_t stream) {
  const float* X   = (const float*)d_in[0];
  const float* Wf  = (const float*)d_in[1];
  const float* bf_ = (const float*)d_in[2];
  const float* Wi  = (const float*)d_in[3];
  const float* bi_ = (const float*)d_in[4];
  const float* Wg  = (const float*)d_in[5];
  const float* bg_ = (const float*)d_in[6];
  const float* Wo  = (const float*)d_in[7];
  const float* bo_ = (const float*)d_in[8];
  float* out = (float*)d_out;

  const size_t WtB   = (size_t)NOUT * KTOT * 2;          // 12.58 MB
  const size_t zBb   = BHSZ * 4;                         // 1 MB zeros
  const size_t flagB = (size_t)T_STEPS * 256 * 4;        // 256 KB
  const size_t XbB   = (size_t)T_STEPS * BATCH * DIN * 2; // 67.1 MB
  const size_t HsB   = (size_t)T_STEPS * BHSZ * 2;       // 134.2 MB

  char* ws = (char*)d_ws;
  bf16*     Wt    = (bf16*)ws;            ws += WtB;
  float*    zbF   = (float*)(void*)ws;    ws += zBb;
  unsigned* flags = (unsigned*)(void*)ws; ws += flagB;

  const bool big = ws_size >= WtB + zBb + flagB + XbB + HsB + (1u << 20);
  bf16* xbp = nullptr;  bf16* hseq = nullptr;
  if (big) {
    xbp  = (bf16*)ws;   ws += XbB;
    hseq = (bf16*)ws;
  }

  hipMemsetAsync(zbF, 0, zBb + flagB, stream);   // zeros + flag array

  convert_w_kernel<<<dim3(KTOT / 64, NOUT / 64), 256, 0, stream>>>(Wf, Wi, Wg, Wo, Wt);

  if (big) {
    convert_x_kernel<<<dim3(BATCH * DIN / 4 / 256, T_STEPS), 256, 0, stream>>>(X, xbp);
    lstm_persist<0><<<256, 512, 0, stream>>>(Wt, X, xbp, hseq, zbF, out,
                                             bf_, bi_, bg_, bo_, flags);
  } else {
    lstm_persist<1><<<256, 512, 0, stream>>>(Wt, X, xbp, hseq, zbF, out,
                                             bf_, bi_, bg_, bo_, flags);
  }

  // hx = outputs[T-1] (cx stored by the kernel)
  hipMemcpyAsync(out + (size_t)T_STEPS * BHSZ, out + (size_t)(T_STEPS - 1) * BHSZ,
                 BHSZ * 4, hipMemcpyDeviceToDevice, stream);
}

// Round 6
// 2464.693 us; speedup vs baseline: 1.3899x; 1.0902x over previous
//
#include <hip/hip_runtime.h>
#include <cstdint>
#include <cstddef>

// Problem constants (fixed by the reference)
#define T_STEPS 256
#define BATCH   256
#define DIN     512
#define HID     1024
#define KTOT    1536   // DIN + HID
#define NOUT    4096   // 4*HID
#define BHSZ    ((size_t)BATCH * HID)   // 262144 elems

typedef __bf16 bf16;
typedef __bf16 bf16x4 __attribute__((ext_vector_type(4)));
typedef __bf16 bf16x8 __attribute__((ext_vector_type(8)));
typedef float  f32x4  __attribute__((ext_vector_type(4)));

// cross-XCD-visible bf16 store (write-through to MALL)
__device__ __forceinline__ void store_bf16_sc(bf16* p, bf16 v) {
  unsigned short u = __builtin_bit_cast(unsigned short, v);
  asm volatile("global_store_short %0, %1, off sc0 sc1" :: "v"(p), "v"(u) : "memory");
}

// ---------------------------------------------------------------------------
// Gate-interleaved transposed weights: Wt[(j>>4)*64 + gate*16 + (j&15)][k]
// (verified rounds 1-4)
__global__ void convert_w_kernel(const float* __restrict__ Wf, const float* __restrict__ Wi,
                                 const float* __restrict__ Wg, const float* __restrict__ Wo,
                                 bf16* __restrict__ Wt) {
  __shared__ float tile[64][17];
  const int k0 = blockIdx.x * 64;
  const int jb = blockIdx.y;
  const int j0 = jb * 16;
  const int t  = threadIdx.x;
  const float* srcs[4] = {Wf, Wi, Wg, Wo};
#pragma unroll
  for (int g = 0; g < 4; ++g) {
    const float* src = srcs[g];
    {
      const int jl = t & 15, kb = t >> 4;
#pragma unroll
      for (int r = 0; r < 4; ++r) {
        const int kl = kb + 16 * r;
        tile[kl][jl] = src[(size_t)(k0 + kl) * HID + (j0 + jl)];
      }
    }
    __syncthreads();
    {
      const int kk = t & 63, jl4 = t >> 6;
#pragma unroll
      for (int r = 0; r < 4; ++r) {
        const int jl = jl4 + 4 * r;
        Wt[(size_t)(jb * 64 + g * 16 + jl) * KTOT + (k0 + kk)] = (bf16)tile[kk][jl];
      }
    }
    __syncthreads();
  }
}

// fp32 -> bf16 convert of X (MODE 0 only)
__global__ void convert_x_kernel(const float* __restrict__ X, bf16* __restrict__ xb) {
  const int t = blockIdx.y;
  const int i = blockIdx.x * blockDim.x + threadIdx.x;
  const float4 v = ((const float4*)(X + (size_t)t * BATCH * DIN))[i];
  bf16x4 o;
  o[0] = (bf16)v.x; o[1] = (bf16)v.y; o[2] = (bf16)v.z; o[3] = (bf16)v.w;
  ((bf16x4*)(xb + (size_t)t * BATCH * DIN))[i] = o;
}

// ---------------------------------------------------------------------------
// Persistent LSTM, B-in-registers edition.
// 256 blocks (1/CU, LDS-forced) x 512 threads (8 waves = 2/SIMD).
// Block: 64 batch rows x 64 Wt rows (16 j x 4 gates). Wave: full 64x64 output
// x a K-eighth as 6 INTERLEAVED 32-k slices (ks = wid + 8*s): slices 0,1 are
// x-only for every wave, slices 2..5 are h -> poll folded before slice-2's
// A-prefetch, all SIMDs stay busy during the handoff window.
// B panel (64 x 1536 bf16 = 192 KiB/CU) lives in VGPRs (breg[6][4], 96/lane)
// for the whole sequence: no LDS staging, no barriers in the K-loop.
// Per step: K-loop (pure A-load + MFMA) -> 128 KB LDS partial dump ->
// 8-way owner reduce -> fused gate epilogue (2 cells/lane, c in VGPRs) ->
// flag handoff (rounds 3-4-proven pattern).
template<int MODE>
__global__ __launch_bounds__(512, 2)
void lstm_persist(const bf16* __restrict__ Bt,
                  const float* __restrict__ X,
                  const bf16* __restrict__ xb,     // MODE 0
                  bf16* __restrict__ hseq,         // MODE 0
                  const float* __restrict__ zbF,   // >= 1MB zeros
                  float* __restrict__ outF,
                  const float* __restrict__ bf_, const float* __restrict__ bi_,
                  const float* __restrict__ bg_, const float* __restrict__ bo_,
                  unsigned* __restrict__ flags) {  // [T_STEPS][256], zeroed
  __shared__ f32x4 redu[8][16][64];   // 128 KiB -> exactly 1 block/CU

  const int tid = threadIdx.x, lane = tid & 63, wid = tid >> 6;
  const int bid = blockIdx.x;
  const int xcd = bid & 7, sl = bid >> 3;
  const int nblk = xcd * 8 + (sl & 7);
  const int mblk = sl >> 3;
  const int bm0 = mblk * 64;
  const int bn0 = nblk * 64;
  const int fr = lane & 15, fq = lane >> 4;

  // once-per-launch agent acquire: invalidate stale L2 lines (cross-launch)
  if (tid == 0)
    (void)__hip_atomic_load(flags, __ATOMIC_ACQUIRE, __HIP_MEMORY_SCOPE_AGENT);
  __syncthreads();

  const int j = nblk * 16 + fr;
  const float bfv = bf_[j], biv = bi_[j], bgv = bg_[j], bov = bo_[j];
  float cr[2] = {0.f, 0.f};

  // ---- B panel -> VGPRs, once. breg[s][nf]: frag for slice ks = wid+8s.
  bf16x8 breg[6][4];
#pragma unroll
  for (int s = 0; s < 6; ++s) {
    const int ks = wid + 8 * s;
#pragma unroll
    for (int nf = 0; nf < 4; ++nf)
      breg[s][nf] = *(const bf16x8*)(Bt + (size_t)(bn0 + nf * 16 + fr) * KTOT
                                     + ks * 32 + fq * 8);
  }

  bf16x8 afp[2][4];   // A frag prefetch (ping-pong)

  auto poll = [&](int tprev) {
    const unsigned* f = flags + (size_t)tprev * 256 + mblk * 64;
    const unsigned long long tt0 = __builtin_amdgcn_s_memrealtime();
    for (;;) {
      unsigned v = __hip_atomic_load(f + lane, __ATOMIC_RELAXED,
                                     __HIP_MEMORY_SCOPE_AGENT);
      if (__all(v != 0)) break;
      __builtin_amdgcn_s_sleep(2);
      if (__builtin_amdgcn_s_memrealtime() - tt0 > (1ULL << 22)) break; // fail-soft
    }
    asm volatile("" ::: "memory");
    __builtin_amdgcn_sched_barrier(0);
  };

  // A-frag loads for slice s of step t2 -> slot p. s is compile-time constant
  // at every call site: s<2 => x-part (ks = wid+8s <= 15), s>=2 => h-part.
  auto loadA = [&](int t2, int s, int p) __attribute__((always_inline)) {
    const int ks = wid + 8 * s;
    const int k = ks * 32 + fq * 8;
    if (s == 2 && t2 > 0) poll(t2 - 1);
    if (MODE == 0) {
      const bf16* src; int ld, kk;
      if (s < 2) { src = xb + (size_t)t2 * BATCH * DIN; ld = DIN; kk = k; }
      else {
        src = (t2 == 0) ? (const bf16*)zbF : hseq + (size_t)(t2 - 1) * BHSZ;
        ld = HID; kk = k - 512;
      }
#pragma unroll
      for (int mf = 0; mf < 4; ++mf)
        afp[p][mf] = *(const bf16x8*)(src + (size_t)(bm0 + mf * 16 + fr) * ld + kk);
    } else {
      const float* src; int ld, kk;
      if (s < 2) { src = X + (size_t)t2 * BATCH * DIN; ld = DIN; kk = k; }
      else {
        src = (t2 == 0) ? zbF : outF + (size_t)(t2 - 1) * BHSZ;
        ld = HID; kk = k - 512;
      }
#pragma unroll
      for (int mf = 0; mf < 4; ++mf) {
        const float* q = src + (size_t)(bm0 + mf * 16 + fr) * ld + kk;
        const f32x4 lo = *(const f32x4*)q;
        const f32x4 hi = *(const f32x4*)(q + 4);
        bf16x8 v;
        v[0] = (bf16)lo[0]; v[1] = (bf16)lo[1]; v[2] = (bf16)lo[2]; v[3] = (bf16)lo[3];
        v[4] = (bf16)hi[0]; v[5] = (bf16)hi[1]; v[6] = (bf16)hi[2]; v[7] = (bf16)hi[3];
        afp[p][mf] = v;
      }
    }
  };

  loadA(0, 0, 0);   // prologue

#pragma unroll 1
  for (int t = 0; t < T_STEPS; ++t) {
    f32x4 acc[4][4] = {};
#pragma unroll
    for (int s = 0; s < 6; ++s) {
      // prefetch next slice (slice-2 call performs the h-ready poll)
      if (s < 5)                loadA(t, s + 1, (s + 1) & 1);
      else if (t + 1 < T_STEPS) loadA(t + 1, 0, 0);
      __builtin_amdgcn_s_setprio(1);
#pragma unroll
      for (int mf = 0; mf < 4; ++mf)
#pragma unroll
        for (int nf = 0; nf < 4; ++nf)
          acc[mf][nf] = __builtin_amdgcn_mfma_f32_16x16x32_bf16(
              afp[s & 1][mf], breg[s][nf], acc[mf][nf], 0, 0, 0);
      __builtin_amdgcn_s_setprio(0);
    }

    // ---- partial dump: wave wid's 16 frag-partials (conflict-free b128)
#pragma unroll
    for (int mf = 0; mf < 4; ++mf)
#pragma unroll
      for (int nf = 0; nf < 4; ++nf)
        redu[wid][mf * 4 + nf][lane] = acc[mf][nf];
    __syncthreads();

    // ---- owner reduce: wave w owns rows bm0 + w*8 .. +8, all 64 N-cols.
    // lane -> cells (rows w*8 + 2*fq + e, col j), e = 0,1.
    const int fbase = (wid >> 1) * 4;    // mf_o * 4
    const int rh = wid & 1;
    float z[2][4];
#pragma unroll
    for (int e = 0; e < 2; ++e) {
      const int rloc = rh * 8 + fq * 2 + e;
      const int lsel = (rloc >> 2) * 16 + fr;
      const int rc = rloc & 3;
#pragma unroll
      for (int nf = 0; nf < 4; ++nf) {
        float sum = 0.f;
#pragma unroll
        for (int s = 0; s < 8; ++s)
          sum += ((const float*)&redu[s][fbase + nf][lsel])[rc];
        z[e][nf] = sum;
      }
    }

    // ---- fused gate epilogue (nf = gate), c/h update, h stores
    float* outSl = outF + (size_t)t * BHSZ;
#pragma unroll
    for (int e = 0; e < 2; ++e) {
      const float fg = 1.f / (1.f + expf(-(z[e][0] + bfv)));
      const float ig = 1.f / (1.f + expf(-(z[e][1] + biv)));
      const float gg = tanhf(z[e][2] + bgv);
      const float og = 1.f / (1.f + expf(-(z[e][3] + bov)));
      cr[e] = fg * cr[e] + ig * gg;
      const float h = og * tanhf(cr[e]);
      const int m = bm0 + wid * 8 + fq * 2 + e;
      const size_t off = (size_t)m * HID + j;
      if (MODE == 0) {
        outSl[off] = h;                                        // harness output
        store_bf16_sc(hseq + (size_t)t * BHSZ + off, (bf16)h); // consumers
      } else {
        __hip_atomic_store(&outSl[off], h, __ATOMIC_RELAXED,
                           __HIP_MEMORY_SCOPE_AGENT);
      }
      if (t == T_STEPS - 1)
        outF[(size_t)(T_STEPS + 1) * BHSZ + off] = cr[e];      // cx
    }
    asm volatile("s_waitcnt vmcnt(0)" ::: "memory");  // h visible at MALL
    __syncthreads();   // also separates owner-reads from next partial dump
    if (tid == 0)
      __hip_atomic_store(&flags[(size_t)t * 256 + mblk * 64 + nblk], 1u,
                         __ATOMIC_RELAXED, __HIP_MEMORY_SCOPE_AGENT);
  }
}

// ---------------------------------------------------------------------------
extern "C" void kernel_launch(void* const* d_in, const int* in_sizes, int n_in,
                              void* d_out, int out_size, void* d_ws, size_t ws_size,
                              hipStream_t stream) {
  const float* X   = (const float*)d_in[0];
  const float* Wf  = (const float*)d_in[1];
  const float* bf_ = (const float*)d_in[2];
  const float* Wi  = (const float*)d_in[3];
  const float* bi_ = (const float*)d_in[4];
  const float* Wg  = (const float*)d_in[5];
  const float* bg_ = (const float*)d_in[6];
  const float* Wo  = (const float*)d_in[7];
  const float* bo_ = (const float*)d_in[8];
  float* out = (float*)d_out;

  const size_t WtB   = (size_t)NOUT * KTOT * 2;           // 12.58 MB
  const size_t zBb   = BHSZ * 4;                          // 1 MB zeros
  const size_t flagB = (size_t)T_STEPS * 256 * 4;         // 256 KB
  const size_t XbB   = (size_t)T_STEPS * BATCH * DIN * 2; // 67.1 MB
  const size_t HsB   = (size_t)T_STEPS * BHSZ * 2;        // 134.2 MB

  char* ws = (char*)d_ws;
  bf16*     Wt    = (bf16*)ws;            ws += WtB;
  float*    zbF   = (float*)(void*)ws;    ws += zBb;
  unsigned* flags = (unsigned*)(void*)ws; ws += flagB;

  const bool big = ws_size >= WtB + zBb + flagB + XbB + HsB + (1u << 20);
  bf16* xbp = nullptr;  bf16* hseq = nullptr;
  if (big) {
    xbp  = (bf16*)ws;   ws += XbB;
    hseq = (bf16*)ws;
  }

  hipMemsetAsync(zbF, 0, zBb + flagB, stream);   // zeros + flag array

  convert_w_kernel<<<dim3(KTOT / 64, NOUT / 64), 256, 0, stream>>>(Wf, Wi, Wg, Wo, Wt);

  if (big) {
    convert_x_kernel<<<dim3(BATCH * DIN / 4 / 256, T_STEPS), 256, 0, stream>>>(X, xbp);
    lstm_persist<0><<<256, 512, 0, stream>>>(Wt, X, xbp, hseq, zbF, out,
                                             bf_, bi_, bg_, bo_, flags);
  } else {
    lstm_persist<1><<<256, 512, 0, stream>>>(Wt, X, xbp, hseq, zbF, out,
                                             bf_, bi_, bg_, bo_, flags);
  }

  // hx = outputs[T-1] (cx stored by the kernel)
  hipMemcpyAsync(out + (size_t)T_STEPS * BHSZ, out + (size_t)(T_STEPS - 1) * BHSZ,
                 BHSZ * 4, hipMemcpyDeviceToDevice, stream);
}